// Round 6
// baseline (2356.140 us; speedup 1.0000x reference)
//
#include <hip/hip_runtime.h>
#include <math.h>

#define NN 100000
#define EE 500000

// ---------------- RTE sinusoid table [240, 256] ----------------
__global__ void rte_tab_kernel(float* __restrict__ tab) {
    int p = blockIdx.x;      // 0..239
    int j = threadIdx.x;     // 0..255
    int m = j >> 1;
    // replicate fp32 overflow: 10000^(2m) -> inf for 2m >= 10 in fp32
    float pf = (float)pow(10000.0, (double)(2 * m));
    float dv = 1.0f / (pf / 128.0f / 2.0f);
    float ang = (float)p * dv;
    const float s = 0.08838834764831845f; // 1/sqrt(128)
    float v = (j & 1) ? (cosf(ang) * s) : (sinf(ang) * s);
    tab[p * 256 + j] = v;
}

// ---------------- rte_proj[p,c] = rte_tab[p,:] @ rte_w + rte_b ----------------
__global__ void rte_proj_kernel(const float* __restrict__ tab,
                                const float* __restrict__ rte_w,
                                const float* __restrict__ rte_b,
                                float* __restrict__ proj) {
    __shared__ float row[256];
    int p = blockIdx.x;           // 240
    int c = threadIdx.x;          // 128
    for (int i = threadIdx.x; i < 256; i += 128) row[i] = tab[p * 256 + i];
    __syncthreads();
    float acc = rte_b[c];
    #pragma unroll 8
    for (int q = 0; q < 256; ++q) acc += row[q] * rte_w[q * 128 + c];
    proj[p * 128 + c] = acc;
}

// ---------------- ktv[b][0:128]=proj@Wk[t], ktv[b][128:256]=proj@Wv[t] ----------------
__global__ void ktv_kernel(const float* __restrict__ proj,
                           const float* __restrict__ Wk,
                           const float* __restrict__ Wv,
                           float* __restrict__ ktv) {
    __shared__ float row[128];
    int b = blockIdx.x;           // 720 = t*240 + p
    int t = b / 240, p = b % 240;
    int c = threadIdx.x;          // 128
    row[c] = proj[p * 128 + c];
    __syncthreads();
    const float* wk = Wk + t * 16384 + c;
    const float* wv = Wv + t * 16384 + c;
    float ak = 0.f, av = 0.f;
    #pragma unroll 8
    for (int q = 0; q < 128; ++q) {
        float rv = row[q];
        ak += rv * wk[q * 128];
        av += rv * wv[q * 128];
    }
    ktv[(size_t)b * 256 + c] = ak;
    ktv[(size_t)b * 256 + 128 + c] = av;
}

// ---------------- CSR build (edges grouped by target) ----------------
__global__ void hist_kernel(const int* __restrict__ tgt, int* __restrict__ cnt) {
    int e = blockIdx.x * blockDim.x + threadIdx.x;
    if (e < EE) atomicAdd(&cnt[tgt[e]], 1);
}

__global__ void scan_kernel(const int* __restrict__ cnt, int* __restrict__ row_start) {
    __shared__ int sdata[1024];
    __shared__ int s_running;
    if (threadIdx.x == 0) s_running = 0;
    __syncthreads();
    for (int base = 0; base < NN; base += 1024) {
        int i = base + (int)threadIdx.x;
        int v = (i < NN) ? cnt[i] : 0;
        sdata[threadIdx.x] = v;
        __syncthreads();
        int acc = v;
        for (int off = 1; off < 1024; off <<= 1) {
            int t = (threadIdx.x >= (unsigned)off) ? sdata[threadIdx.x - off] : 0;
            __syncthreads();
            acc += t;
            sdata[threadIdx.x] = acc;
            __syncthreads();
        }
        int run = s_running;
        if (i < NN) row_start[i] = run + acc - v;   // exclusive
        __syncthreads();
        if (threadIdx.x == 1023) s_running = run + sdata[1023];
        __syncthreads();
    }
    if (threadIdx.x == 0) row_start[NN] = s_running;
}

// scatter + meta fused: meta[pos] = {src, (tb<<6)|(tt<<4)|(st<<2)|r, tgt, 0}
__global__ void scatter_meta_kernel(const int* __restrict__ esrc,
                                    const int* __restrict__ etgt,
                                    const int* __restrict__ etype,
                                    const int* __restrict__ etime,
                                    const int* __restrict__ node_type,
                                    const int* __restrict__ row_start,
                                    int* __restrict__ fill,
                                    int4* __restrict__ meta) {
    int e = blockIdx.x * blockDim.x + threadIdx.x;
    if (e < EE) {
        int tgt = etgt[e];
        int src = esrc[e];
        int r = etype[e];
        int tm = etime[e];
        int st = node_type[src];
        int tt = node_type[tgt];
        int tb = st * 240 + tm;
        int pos = row_start[tgt] + atomicAdd(&fill[tgt], 1);
        meta[pos] = make_int4(src, (tb << 6) | (tt << 4) | (st << 2) | r, tgt, 0);
    }
}

// ---------------- node counting sort by type (3 bins) ----------------
__global__ void node_hist_kernel(const int* __restrict__ nt, int* __restrict__ tcnt) {
    __shared__ int lc[3];
    if (threadIdx.x < 3) lc[threadIdx.x] = 0;
    __syncthreads();
    int i = blockIdx.x * blockDim.x + threadIdx.x;
    if (i < NN) atomicAdd(&lc[nt[i]], 1);
    __syncthreads();
    if (threadIdx.x < 3) atomicAdd(&tcnt[threadIdx.x], lc[threadIdx.x]);
}

__global__ void node_scatter_kernel(const int* __restrict__ nt,
                                    const int* __restrict__ tcnt,
                                    int* __restrict__ fill3,
                                    int* __restrict__ order) {
    __shared__ int lc[3], lbase[3], lfill[3];
    if (threadIdx.x < 3) { lc[threadIdx.x] = 0; lfill[threadIdx.x] = 0; }
    __syncthreads();
    int i = blockIdx.x * blockDim.x + threadIdx.x;
    int t = -1;
    if (i < NN) { t = nt[i]; atomicAdd(&lc[t], 1); }
    __syncthreads();
    if (threadIdx.x < 3) lbase[threadIdx.x] = atomicAdd(&fill3[threadIdx.x], lc[threadIdx.x]);
    __syncthreads();
    if (i < NN) {
        int rank = atomicAdd(&lfill[t], 1);
        int tb = (t == 0) ? 0 : ((t == 1) ? tcnt[0] : tcnt[0] + tcnt[1]);
        order[tb + lbase[t] + rank] = i;
    }
}

// ---------------- typed linear over type-sorted nodes ----------------
template <int MODE>
__global__ __launch_bounds__(256) void typed_lin_kernel(
    const float* __restrict__ in, const int* __restrict__ nt,
    const int* __restrict__ order,
    const float* __restrict__ W, const float* __restrict__ b,
    const float* __restrict__ skip, float* __restrict__ out) {
    __shared__ float xs[32][128];
    __shared__ int rows[32];
    __shared__ int sty[32];
    int nb = blockIdx.x * 32;
    if (threadIdx.x < 32) {
        int r = order[nb + threadIdx.x];
        rows[threadIdx.x] = r;
        sty[threadIdx.x] = nt[r];
    }
    __syncthreads();
    for (int i = threadIdx.x; i < 1024; i += 256) {
        int nl = i >> 5, e4 = i & 31;
        *(float4*)&xs[nl][e4 * 4] = *(const float4*)(in + (size_t)rows[nl] * 128 + e4 * 4);
    }
    __syncthreads();
    int col = threadIdx.x & 127;
    int ng  = (threadIdx.x >> 7) * 16;
    int t0 = sty[ng];
    bool uni = true;
    #pragma unroll
    for (int ii = 1; ii < 16; ++ii) uni &= (sty[ng + ii] == t0);
    if (uni) {
        const float* w = W + t0 * 16384 + col;
        float bv = b[t0 * 128 + col];
        float alpha = (MODE == 1) ? (1.f / (1.f + __expf(-skip[t0]))) : 0.f;
        float acc[16];
        #pragma unroll
        for (int ii = 0; ii < 16; ++ii) acc[ii] = bv;
        for (int k0 = 0; k0 < 128; k0 += 4) {
            float w0 = w[(k0 + 0) * 128];
            float w1 = w[(k0 + 1) * 128];
            float w2 = w[(k0 + 2) * 128];
            float w3 = w[(k0 + 3) * 128];
            #pragma unroll
            for (int ii = 0; ii < 16; ++ii) {
                float4 xv = *(const float4*)&xs[ng + ii][k0];
                acc[ii] += xv.x * w0 + xv.y * w1 + xv.z * w2 + xv.w * w3;
            }
        }
        #pragma unroll
        for (int ii = 0; ii < 16; ++ii) {
            size_t gi = (size_t)rows[ng + ii] * 128 + col;
            if (MODE == 0) out[gi] = tanhf(acc[ii]);
            else           out[gi] = alpha * acc[ii] + (1.f - alpha) * out[gi];
        }
    } else {
        for (int ii = 0; ii < 16; ++ii) {
            int nl = ng + ii;
            int t = sty[nl];
            const float* w = W + t * 16384 + col;
            float acc = b[t * 128 + col];
            #pragma unroll 8
            for (int k = 0; k < 128; ++k) acc += xs[nl][k] * w[k * 128];
            size_t gi = (size_t)rows[nl] * 128 + col;
            if (MODE == 0) out[gi] = tanhf(acc);
            else {
                float alpha = 1.f / (1.f + __expf(-skip[t]));
                out[gi] = alpha * acc + (1.f - alpha) * out[gi];
            }
        }
    }
}

// ---------------- fused Q/K/V typed projections; K/V interleaved per row ----------------
__global__ __launch_bounds__(256) void qkv_kernel(
    const float* __restrict__ x, const int* __restrict__ nt,
    const int* __restrict__ order,
    const float* __restrict__ Wq, const float* __restrict__ bq,
    const float* __restrict__ Wk, const float* __restrict__ bk,
    const float* __restrict__ Wv, const float* __restrict__ bv,
    float* __restrict__ Qn, float* __restrict__ KV) {
    __shared__ float xs[32][128];
    __shared__ int rows[32];
    __shared__ int sty[32];
    int nb = blockIdx.x * 32;
    if (threadIdx.x < 32) {
        int r = order[nb + threadIdx.x];
        rows[threadIdx.x] = r;
        sty[threadIdx.x] = nt[r];
    }
    __syncthreads();
    for (int i = threadIdx.x; i < 1024; i += 256) {
        int nl = i >> 5, e4 = i & 31;
        *(float4*)&xs[nl][e4 * 4] = *(const float4*)(x + (size_t)rows[nl] * 128 + e4 * 4);
    }
    __syncthreads();
    int col = threadIdx.x & 127;
    int ng  = (threadIdx.x >> 7) * 16;
    int t0 = sty[ng];
    bool uni = true;
    #pragma unroll
    for (int ii = 1; ii < 16; ++ii) uni &= (sty[ng + ii] == t0);
    if (uni) {
        const float* wq = Wq + t0 * 16384 + col;
        const float* wk = Wk + t0 * 16384 + col;
        const float* wv = Wv + t0 * 16384 + col;
        float bqv = bq[t0 * 128 + col];
        float bkv = bk[t0 * 128 + col];
        float bvv = bv[t0 * 128 + col];
        float aq[16], ak[16], av[16];
        #pragma unroll
        for (int ii = 0; ii < 16; ++ii) { aq[ii] = bqv; ak[ii] = bkv; av[ii] = bvv; }
        for (int k0 = 0; k0 < 128; k0 += 4) {
            float q0 = wq[(k0 + 0) * 128], q1 = wq[(k0 + 1) * 128];
            float q2 = wq[(k0 + 2) * 128], q3 = wq[(k0 + 3) * 128];
            float k0w = wk[(k0 + 0) * 128], k1w = wk[(k0 + 1) * 128];
            float k2w = wk[(k0 + 2) * 128], k3w = wk[(k0 + 3) * 128];
            float v0 = wv[(k0 + 0) * 128], v1 = wv[(k0 + 1) * 128];
            float v2 = wv[(k0 + 2) * 128], v3 = wv[(k0 + 3) * 128];
            #pragma unroll
            for (int ii = 0; ii < 16; ++ii) {
                float4 xv = *(const float4*)&xs[ng + ii][k0];
                aq[ii] += xv.x * q0 + xv.y * q1 + xv.z * q2 + xv.w * q3;
                ak[ii] += xv.x * k0w + xv.y * k1w + xv.z * k2w + xv.w * k3w;
                av[ii] += xv.x * v0 + xv.y * v1 + xv.z * v2 + xv.w * v3;
            }
        }
        #pragma unroll
        for (int ii = 0; ii < 16; ++ii) {
            size_t row = (size_t)rows[ng + ii];
            Qn[row * 128 + col] = aq[ii];
            KV[row * 256 + col] = ak[ii];
            KV[row * 256 + 128 + col] = av[ii];
        }
    } else {
        for (int ii = 0; ii < 16; ++ii) {
            int nl = ng + ii;
            int t = sty[nl];
            const float* wq = Wq + t * 16384 + col;
            const float* wk = Wk + t * 16384 + col;
            const float* wv = Wv + t * 16384 + col;
            float aq = bq[t * 128 + col];
            float ak = bk[t * 128 + col];
            float av = bv[t * 128 + col];
            #pragma unroll 4
            for (int k = 0; k < 128; ++k) {
                float xv = xs[nl][k];
                aq += xv * wq[k * 128];
                ak += xv * wk[k * 128];
                av += xv * wv[k * 128];
            }
            size_t row = (size_t)rows[nl];
            Qn[row * 128 + col] = aq;
            KV[row * 256 + col] = ak;
            KV[row * 256 + 128 + col] = av;
        }
    }
}

// ---------------- edge-parallel score pass: p[it*8+h] = exp(score*pri/4) ----------------
__global__ __launch_bounds__(256) void score_kernel(
    const float* __restrict__ Qn, const float* __restrict__ KV,
    const float* __restrict__ ktv, const int4* __restrict__ meta,
    const float* __restrict__ rel_pri, const float* __restrict__ rel_att,
    float* __restrict__ p_out) {
    int gid = blockIdx.x * 256 + threadIdx.x;
    if (gid >= EE * 8) return;
    int it = gid >> 3, h = gid & 7;
    int4 m = meta[it];
    int src = m.x, code = m.y, tgt = m.z;
    int r = code & 3, st = (code >> 2) & 3, tt = (code >> 4) & 3, tb = code >> 6;
    const float4* qp = (const float4*)(Qn + (size_t)tgt * 128 + h * 16);
    const float4* kp = (const float4*)(KV + (size_t)src * 256 + h * 16);
    const float4* tp = (const float4*)(ktv + (size_t)tb * 256 + h * 16);
    float q[16], k[16];
    #pragma unroll
    for (int j = 0; j < 4; ++j) {
        float4 qv = qp[j];
        float4 kv = kp[j];
        float4 tv = tp[j];
        q[4 * j] = qv.x; q[4 * j + 1] = qv.y; q[4 * j + 2] = qv.z; q[4 * j + 3] = qv.w;
        k[4 * j] = kv.x + tv.x; k[4 * j + 1] = kv.y + tv.y;
        k[4 * j + 2] = kv.z + tv.z; k[4 * j + 3] = kv.w + tv.w;
    }
    // score = sum_i k_i * (A[r,h,i,:] . q)
    const float4* A = (const float4*)(rel_att + (size_t)(r * 8 + h) * 256);
    float s = 0.f;
    #pragma unroll
    for (int i = 0; i < 16; ++i) {
        float4 a0 = A[i * 4 + 0], a1 = A[i * 4 + 1], a2 = A[i * 4 + 2], a3 = A[i * 4 + 3];
        float d = a0.x * q[0] + a0.y * q[1] + a0.z * q[2] + a0.w * q[3]
                + a1.x * q[4] + a1.y * q[5] + a1.z * q[6] + a1.w * q[7]
                + a2.x * q[8] + a2.y * q[9] + a2.z * q[10] + a2.w * q[11]
                + a3.x * q[12] + a3.y * q[13] + a3.z * q[14] + a3.w * q[15];
        s += k[i] * d;
    }
    float pri = rel_pri[((tt * 4 + r) * 3 + st) * 8 + h];
    p_out[gid] = __expf(s * pri * 0.25f);
}

// ---------------- lsum pass: inv[n*8+h] = 1/sum_e p ----------------
__global__ __launch_bounds__(256) void lsum_kernel(
    const float* __restrict__ p, const int* __restrict__ row_start,
    float* __restrict__ inv) {
    int gid = blockIdx.x * 256 + threadIdx.x;
    if (gid >= NN * 8) return;
    int n = gid >> 3, h = gid & 7;
    float s = 0.f;
    int e_end = row_start[n + 1];
    for (int it = row_start[n]; it < e_end; ++it) s += p[it * 8 + h];
    inv[gid] = (s > 0.f) ? (1.f / s) : 0.f;
}

// ---------------- aggregation: wave per node; per-relation register accums;
// epilogue applies rel_msg via LDS (parallel across lanes, no shuffles) ----------------
__global__ __launch_bounds__(256) void aggr_kernel(
    const float* __restrict__ KV, const float* __restrict__ ktv,
    const int4* __restrict__ meta, const float* __restrict__ p,
    const float* __restrict__ inv, const int* __restrict__ row_start,
    const float* __restrict__ rel_msg, float* __restrict__ h_out) {
    __shared__ float accb[4][4][136];   // [wave][r][h*17 + cp] padded vs bank conflicts
    int w = threadIdx.x >> 6;
    int n = blockIdx.x * 4 + w;          // grid = NN/4 exactly; no early return (barrier!)
    int lane = threadIdx.x & 63;
    int d0 = lane * 2;
    int h = lane >> 3;
    int cp = d0 & 15;
    int e_beg = row_start[n], e_end = row_start[n + 1];
    float2 a0 = {0.f, 0.f}, a1 = {0.f, 0.f}, a2 = {0.f, 0.f}, a3 = {0.f, 0.f};
    int rmask = 0;
    for (int cb = e_beg; cb < e_end; cb += 64) {
        int cdeg = min(64, e_end - cb);
        int4 mm = (cb + lane < e_end) ? meta[cb + lane] : make_int4(0, 0, 0, 0);
        int mx = mm.x, my = mm.y;
        #pragma unroll 4
        for (int i = 0; i < cdeg; ++i) {
            int src  = __shfl(mx, i, 64);
            int code = __shfl(my, i, 64);
            int r = code & 3;
            float pv = p[(size_t)(cb + i) * 8 + h];
            float2 v1 = *(const float2*)(KV + (size_t)src * 256 + 128 + d0);
            float2 v2 = *(const float2*)(ktv + (size_t)(code >> 6) * 256 + 128 + d0);
            float vx = pv * (v1.x + v2.x);
            float vy = pv * (v1.y + v2.y);
            rmask |= (1 << r);
            switch (r) {
                case 0: a0.x += vx; a0.y += vy; break;
                case 1: a1.x += vx; a1.y += vy; break;
                case 2: a2.x += vx; a2.y += vy; break;
                default: a3.x += vx; a3.y += vy; break;
            }
        }
    }
    int li = h * 17 + cp;
    accb[w][0][li] = a0.x; accb[w][0][li + 1] = a0.y;
    accb[w][1][li] = a1.x; accb[w][1][li + 1] = a1.y;
    accb[w][2][li] = a2.x; accb[w][2][li + 1] = a2.y;
    accb[w][3][li] = a3.x; accb[w][3][li + 1] = a3.y;
    __syncthreads();
    // o[c] = sum_r sum_i acc_r[h*16+i] * rel_msg[r,h,i,c]
    float o0 = 0.f, o1 = 0.f;
    const float* M = rel_msg + h * 256 + cp;
    #pragma unroll
    for (int r = 0; r < 4; ++r) {
        if (rmask & (1 << r)) {
            #pragma unroll
            for (int i = 0; i < 16; ++i) {
                float av = accb[w][r][h * 17 + i];
                float2 mm2 = *(const float2*)(M + r * 2048 + i * 16);
                o0 += av * mm2.x;
                o1 += av * mm2.y;
            }
        }
    }
    float iv = inv[n * 8 + h];
    o0 *= iv; o1 *= iv;
    // exact gelu
    o0 = 0.5f * o0 * (1.f + erff(o0 * 0.7071067811865475f));
    o1 = 0.5f * o1 * (1.f + erff(o1 * 0.7071067811865475f));
    *(float2*)(h_out + (size_t)n * 128 + d0) = make_float2(o0, o1);
}

// ---------------- launcher ----------------
extern "C" void kernel_launch(void* const* d_in, const int* in_sizes, int n_in,
                              void* d_out, int out_size, void* d_ws, size_t ws_size,
                              hipStream_t stream) {
    const float* node_feature = (const float*)d_in[0];
    const int*   node_type    = (const int*)d_in[1];
    const int*   edge_index   = (const int*)d_in[2];   // [2,E]: src then tgt
    const int*   edge_type    = (const int*)d_in[3];
    const int*   edge_time    = (const int*)d_in[4];
    const float* adapt_w      = (const float*)d_in[5];
    const float* adapt_b      = (const float*)d_in[6];
    const float* Wk           = (const float*)d_in[7];
    const float* bk           = (const float*)d_in[8];
    const float* Wq           = (const float*)d_in[9];
    const float* bq           = (const float*)d_in[10];
    const float* Wv           = (const float*)d_in[11];
    const float* bv           = (const float*)d_in[12];
    const float* Wa           = (const float*)d_in[13];
    const float* ba           = (const float*)d_in[14];
    const float* rel_pri      = (const float*)d_in[15];
    const float* rel_att      = (const float*)d_in[16];
    const float* rel_msg      = (const float*)d_in[17];
    const float* skip         = (const float*)d_in[18];
    const float* rte_w        = (const float*)d_in[19];
    const float* rte_b        = (const float*)d_in[20];
    float* out = (float*)d_out;

    const size_t ND = (size_t)NN * 128;
    float* Qn     = (float*)d_ws;            // N*128 (reused as h buffer)
    float* KV     = Qn + ND;                 // N*256 (k|v per row)
    float* rtab   = KV + 2 * ND;             // 240*256
    float* rproj  = rtab + 240 * 256;        // 240*128
    float* ktv    = rproj + 240 * 128;       // 720*256 (k|v per row)
    float* pbuf   = ktv + 720 * 256;         // EE*8
    float* invl   = pbuf + (size_t)EE * 8;   // NN*8
    int*   cnt    = (int*)(invl + (size_t)NN * 8);
    int*   fill   = cnt + NN;
    int*   row_st = fill + NN;               // NN+1 (+pad)
    int*   order  = row_st + NN + 4;         // NN
    int*   tcnt   = order + NN;              // 3 (+pad)
    int*   fill3  = tcnt + 4;                // 3 (+pad)
    int4*  meta   = (int4*)(fill3 + 4);      // EE int4
    // total ~184 MB (R5's 342 MB crashed; R4's 165 MB worked)

    const int* esrc = edge_index;
    const int* etgt = edge_index + EE;

    hipMemsetAsync(cnt, 0, 2 * NN * sizeof(int), stream);
    hipMemsetAsync(tcnt, 0, 8 * sizeof(int), stream);
    rte_tab_kernel<<<240, 256, 0, stream>>>(rtab);
    hist_kernel<<<(EE + 255) / 256, 256, 0, stream>>>(etgt, cnt);
    scan_kernel<<<1, 1024, 0, stream>>>(cnt, row_st);
    scatter_meta_kernel<<<(EE + 255) / 256, 256, 0, stream>>>(esrc, etgt, edge_type,
                                                              edge_time, node_type,
                                                              row_st, fill, meta);
    node_hist_kernel<<<(NN + 255) / 256, 256, 0, stream>>>(node_type, tcnt);
    node_scatter_kernel<<<(NN + 255) / 256, 256, 0, stream>>>(node_type, tcnt, fill3, order);

    // input adaptation: x = tanh(typed_linear(node_feature))
    typed_lin_kernel<0><<<NN / 32, 256, 0, stream>>>(node_feature, node_type, order,
                                                     adapt_w, adapt_b, nullptr, out);

    for (int l = 0; l < 2; ++l) {
        const float* Wk_l = Wk + l * 49152;  const float* bk_l = bk + l * 384;
        const float* Wq_l = Wq + l * 49152;  const float* bq_l = bq + l * 384;
        const float* Wv_l = Wv + l * 49152;  const float* bv_l = bv + l * 384;
        const float* Wa_l = Wa + l * 49152;  const float* ba_l = ba + l * 384;
        const float* pri_l = rel_pri + l * 288;
        const float* att_l = rel_att + l * 8192;
        const float* msg_l = rel_msg + l * 8192;
        const float* skip_l = skip + l * 3;
        const float* rte_w_l = rte_w + l * 32768;
        const float* rte_b_l = rte_b + l * 128;

        rte_proj_kernel<<<240, 128, 0, stream>>>(rtab, rte_w_l, rte_b_l, rproj);
        ktv_kernel<<<720, 128, 0, stream>>>(rproj, Wk_l, Wv_l, ktv);
        qkv_kernel<<<NN / 32, 256, 0, stream>>>(out, node_type, order, Wq_l, bq_l,
                                                Wk_l, bk_l, Wv_l, bv_l, Qn, KV);
        score_kernel<<<(EE * 8) / 256, 256, 0, stream>>>(Qn, KV, ktv, meta,
                                                         pri_l, att_l, pbuf);
        lsum_kernel<<<(NN * 8 + 255) / 256, 256, 0, stream>>>(pbuf, row_st, invl);
        aggr_kernel<<<NN / 4, 256, 0, stream>>>(KV, ktv, meta, pbuf, invl, row_st,
                                                msg_l, Qn /* h overwrites Qn: safe */);
        typed_lin_kernel<1><<<NN / 32, 256, 0, stream>>>(Qn, node_type, order, Wa_l, ba_l,
                                                         skip_l, out);
    }
}

// Round 7
// 1868.021 us; speedup vs baseline: 1.2613x; 1.2613x over previous
//
#include <hip/hip_runtime.h>
#include <math.h>

#define NN 100000
#define EE 500000

// ---------------- RTE sinusoid table [240, 256] ----------------
__global__ void rte_tab_kernel(float* __restrict__ tab) {
    int p = blockIdx.x;      // 0..239
    int j = threadIdx.x;     // 0..255
    int m = j >> 1;
    // replicate fp32 overflow: 10000^(2m) -> inf for 2m >= 10 in fp32
    float pf = (float)pow(10000.0, (double)(2 * m));
    float dv = 1.0f / (pf / 128.0f / 2.0f);
    float ang = (float)p * dv;
    const float s = 0.08838834764831845f; // 1/sqrt(128)
    float v = (j & 1) ? (cosf(ang) * s) : (sinf(ang) * s);
    tab[p * 256 + j] = v;
}

// ---------------- rte_proj[p,c] = rte_tab[p,:] @ rte_w + rte_b ----------------
__global__ void rte_proj_kernel(const float* __restrict__ tab,
                                const float* __restrict__ rte_w,
                                const float* __restrict__ rte_b,
                                float* __restrict__ proj) {
    __shared__ float row[256];
    int p = blockIdx.x;           // 240
    int c = threadIdx.x;          // 128
    for (int i = threadIdx.x; i < 256; i += 128) row[i] = tab[p * 256 + i];
    __syncthreads();
    float acc = rte_b[c];
    #pragma unroll 8
    for (int q = 0; q < 256; ++q) acc += row[q] * rte_w[q * 128 + c];
    proj[p * 128 + c] = acc;
}

// ---------------- ktv[b][0:128]=proj@Wk[t], ktv[b][128:256]=proj@Wv[t] ----------------
__global__ void ktv_kernel(const float* __restrict__ proj,
                           const float* __restrict__ Wk,
                           const float* __restrict__ Wv,
                           float* __restrict__ ktv) {
    __shared__ float row[128];
    int b = blockIdx.x;           // 720 = t*240 + p
    int t = b / 240, p = b % 240;
    int c = threadIdx.x;          // 128
    row[c] = proj[p * 128 + c];
    __syncthreads();
    const float* wk = Wk + t * 16384 + c;
    const float* wv = Wv + t * 16384 + c;
    float ak = 0.f, av = 0.f;
    #pragma unroll 8
    for (int q = 0; q < 128; ++q) {
        float rv = row[q];
        ak += rv * wk[q * 128];
        av += rv * wv[q * 128];
    }
    ktv[(size_t)b * 256 + c] = ak;
    ktv[(size_t)b * 256 + 128 + c] = av;
}

// ---------------- CSR build (edges grouped by target) ----------------
__global__ void hist_kernel(const int* __restrict__ tgt, int* __restrict__ cnt) {
    int e = blockIdx.x * blockDim.x + threadIdx.x;
    if (e < EE) atomicAdd(&cnt[tgt[e]], 1);
}

__global__ void scan_kernel(const int* __restrict__ cnt, int* __restrict__ row_start) {
    __shared__ int sdata[1024];
    __shared__ int s_running;
    if (threadIdx.x == 0) s_running = 0;
    __syncthreads();
    for (int base = 0; base < NN; base += 1024) {
        int i = base + (int)threadIdx.x;
        int v = (i < NN) ? cnt[i] : 0;
        sdata[threadIdx.x] = v;
        __syncthreads();
        int acc = v;
        for (int off = 1; off < 1024; off <<= 1) {
            int t = (threadIdx.x >= (unsigned)off) ? sdata[threadIdx.x - off] : 0;
            __syncthreads();
            acc += t;
            sdata[threadIdx.x] = acc;
            __syncthreads();
        }
        int run = s_running;
        if (i < NN) row_start[i] = run + acc - v;   // exclusive
        __syncthreads();
        if (threadIdx.x == 1023) s_running = run + sdata[1023];
        __syncthreads();
    }
    if (threadIdx.x == 0) row_start[NN] = s_running;
}

// scatter + meta fused: meta[pos] = {src, (tb<<6)|(tt<<4)|(st<<2)|r, tgt, 0}
__global__ void scatter_meta_kernel(const int* __restrict__ esrc,
                                    const int* __restrict__ etgt,
                                    const int* __restrict__ etype,
                                    const int* __restrict__ etime,
                                    const int* __restrict__ node_type,
                                    const int* __restrict__ row_start,
                                    int* __restrict__ fill,
                                    int4* __restrict__ meta) {
    int e = blockIdx.x * blockDim.x + threadIdx.x;
    if (e < EE) {
        int tgt = etgt[e];
        int src = esrc[e];
        int r = etype[e];
        int tm = etime[e];
        int st = node_type[src];
        int tt = node_type[tgt];
        int tb = st * 240 + tm;
        int pos = row_start[tgt] + atomicAdd(&fill[tgt], 1);
        meta[pos] = make_int4(src, (tb << 6) | (tt << 4) | (st << 2) | r, tgt, 0);
    }
}

// ---------------- node counting sort by type (3 bins) ----------------
__global__ void node_hist_kernel(const int* __restrict__ nt, int* __restrict__ tcnt) {
    __shared__ int lc[3];
    if (threadIdx.x < 3) lc[threadIdx.x] = 0;
    __syncthreads();
    int i = blockIdx.x * blockDim.x + threadIdx.x;
    if (i < NN) atomicAdd(&lc[nt[i]], 1);
    __syncthreads();
    if (threadIdx.x < 3) atomicAdd(&tcnt[threadIdx.x], lc[threadIdx.x]);
}

__global__ void node_scatter_kernel(const int* __restrict__ nt,
                                    const int* __restrict__ tcnt,
                                    int* __restrict__ fill3,
                                    int* __restrict__ order) {
    __shared__ int lc[3], lbase[3], lfill[3];
    if (threadIdx.x < 3) { lc[threadIdx.x] = 0; lfill[threadIdx.x] = 0; }
    __syncthreads();
    int i = blockIdx.x * blockDim.x + threadIdx.x;
    int t = -1;
    if (i < NN) { t = nt[i]; atomicAdd(&lc[t], 1); }
    __syncthreads();
    if (threadIdx.x < 3) lbase[threadIdx.x] = atomicAdd(&fill3[threadIdx.x], lc[threadIdx.x]);
    __syncthreads();
    if (i < NN) {
        int rank = atomicAdd(&lfill[t], 1);
        int tb = (t == 0) ? 0 : ((t == 1) ? tcnt[0] : tcnt[0] + tcnt[1]);
        order[tb + lbase[t] + rank] = i;
    }
}

// ---------------- typed linear over type-sorted nodes ----------------
template <int MODE>
__global__ __launch_bounds__(256) void typed_lin_kernel(
    const float* __restrict__ in, const int* __restrict__ nt,
    const int* __restrict__ order,
    const float* __restrict__ W, const float* __restrict__ b,
    const float* __restrict__ skip, float* __restrict__ out) {
    __shared__ float xs[32][128];
    __shared__ int rows[32];
    __shared__ int sty[32];
    int nb = blockIdx.x * 32;
    if (threadIdx.x < 32) {
        int r = order[nb + threadIdx.x];
        rows[threadIdx.x] = r;
        sty[threadIdx.x] = nt[r];
    }
    __syncthreads();
    for (int i = threadIdx.x; i < 1024; i += 256) {
        int nl = i >> 5, e4 = i & 31;
        *(float4*)&xs[nl][e4 * 4] = *(const float4*)(in + (size_t)rows[nl] * 128 + e4 * 4);
    }
    __syncthreads();
    int col = threadIdx.x & 127;
    int ng  = (threadIdx.x >> 7) * 16;
    int t0 = sty[ng];
    bool uni = true;
    #pragma unroll
    for (int ii = 1; ii < 16; ++ii) uni &= (sty[ng + ii] == t0);
    if (uni) {
        const float* w = W + t0 * 16384 + col;
        float bv = b[t0 * 128 + col];
        float alpha = (MODE == 1) ? (1.f / (1.f + __expf(-skip[t0]))) : 0.f;
        float acc[16];
        #pragma unroll
        for (int ii = 0; ii < 16; ++ii) acc[ii] = bv;
        for (int k0 = 0; k0 < 128; k0 += 4) {
            float w0 = w[(k0 + 0) * 128];
            float w1 = w[(k0 + 1) * 128];
            float w2 = w[(k0 + 2) * 128];
            float w3 = w[(k0 + 3) * 128];
            #pragma unroll
            for (int ii = 0; ii < 16; ++ii) {
                float4 xv = *(const float4*)&xs[ng + ii][k0];
                acc[ii] += xv.x * w0 + xv.y * w1 + xv.z * w2 + xv.w * w3;
            }
        }
        #pragma unroll
        for (int ii = 0; ii < 16; ++ii) {
            size_t gi = (size_t)rows[ng + ii] * 128 + col;
            if (MODE == 0) out[gi] = tanhf(acc[ii]);
            else           out[gi] = alpha * acc[ii] + (1.f - alpha) * out[gi];
        }
    } else {
        for (int ii = 0; ii < 16; ++ii) {
            int nl = ng + ii;
            int t = sty[nl];
            const float* w = W + t * 16384 + col;
            float acc = b[t * 128 + col];
            #pragma unroll 8
            for (int k = 0; k < 128; ++k) acc += xs[nl][k] * w[k * 128];
            size_t gi = (size_t)rows[nl] * 128 + col;
            if (MODE == 0) out[gi] = tanhf(acc);
            else {
                float alpha = 1.f / (1.f + __expf(-skip[t]));
                out[gi] = alpha * acc + (1.f - alpha) * out[gi];
            }
        }
    }
}

// ---------------- fused Q/K/V typed projections; K/V interleaved per row ----------------
__global__ __launch_bounds__(256) void qkv_kernel(
    const float* __restrict__ x, const int* __restrict__ nt,
    const int* __restrict__ order,
    const float* __restrict__ Wq, const float* __restrict__ bq,
    const float* __restrict__ Wk, const float* __restrict__ bk,
    const float* __restrict__ Wv, const float* __restrict__ bv,
    float* __restrict__ Qn, float* __restrict__ KV) {
    __shared__ float xs[32][128];
    __shared__ int rows[32];
    __shared__ int sty[32];
    int nb = blockIdx.x * 32;
    if (threadIdx.x < 32) {
        int r = order[nb + threadIdx.x];
        rows[threadIdx.x] = r;
        sty[threadIdx.x] = nt[r];
    }
    __syncthreads();
    for (int i = threadIdx.x; i < 1024; i += 256) {
        int nl = i >> 5, e4 = i & 31;
        *(float4*)&xs[nl][e4 * 4] = *(const float4*)(x + (size_t)rows[nl] * 128 + e4 * 4);
    }
    __syncthreads();
    int col = threadIdx.x & 127;
    int ng  = (threadIdx.x >> 7) * 16;
    int t0 = sty[ng];
    bool uni = true;
    #pragma unroll
    for (int ii = 1; ii < 16; ++ii) uni &= (sty[ng + ii] == t0);
    if (uni) {
        const float* wq = Wq + t0 * 16384 + col;
        const float* wk = Wk + t0 * 16384 + col;
        const float* wv = Wv + t0 * 16384 + col;
        float bqv = bq[t0 * 128 + col];
        float bkv = bk[t0 * 128 + col];
        float bvv = bv[t0 * 128 + col];
        float aq[16], ak[16], av[16];
        #pragma unroll
        for (int ii = 0; ii < 16; ++ii) { aq[ii] = bqv; ak[ii] = bkv; av[ii] = bvv; }
        for (int k0 = 0; k0 < 128; k0 += 4) {
            float q0 = wq[(k0 + 0) * 128], q1 = wq[(k0 + 1) * 128];
            float q2 = wq[(k0 + 2) * 128], q3 = wq[(k0 + 3) * 128];
            float k0w = wk[(k0 + 0) * 128], k1w = wk[(k0 + 1) * 128];
            float k2w = wk[(k0 + 2) * 128], k3w = wk[(k0 + 3) * 128];
            float v0 = wv[(k0 + 0) * 128], v1 = wv[(k0 + 1) * 128];
            float v2 = wv[(k0 + 2) * 128], v3 = wv[(k0 + 3) * 128];
            #pragma unroll
            for (int ii = 0; ii < 16; ++ii) {
                float4 xv = *(const float4*)&xs[ng + ii][k0];
                aq[ii] += xv.x * q0 + xv.y * q1 + xv.z * q2 + xv.w * q3;
                ak[ii] += xv.x * k0w + xv.y * k1w + xv.z * k2w + xv.w * k3w;
                av[ii] += xv.x * v0 + xv.y * v1 + xv.z * v2 + xv.w * v3;
            }
        }
        #pragma unroll
        for (int ii = 0; ii < 16; ++ii) {
            size_t row = (size_t)rows[ng + ii];
            Qn[row * 128 + col] = aq[ii];
            KV[row * 256 + col] = ak[ii];
            KV[row * 256 + 128 + col] = av[ii];
        }
    } else {
        for (int ii = 0; ii < 16; ++ii) {
            int nl = ng + ii;
            int t = sty[nl];
            const float* wq = Wq + t * 16384 + col;
            const float* wk = Wk + t * 16384 + col;
            const float* wv = Wv + t * 16384 + col;
            float aq = bq[t * 128 + col];
            float ak = bk[t * 128 + col];
            float av = bv[t * 128 + col];
            #pragma unroll 4
            for (int k = 0; k < 128; ++k) {
                float xv = xs[nl][k];
                aq += xv * wq[k * 128];
                ak += xv * wk[k * 128];
                av += xv * wv[k * 128];
            }
            size_t row = (size_t)rows[nl];
            Qn[row * 128 + col] = aq;
            KV[row * 256 + col] = ak;
            KV[row * 256 + 128 + col] = av;
        }
    }
}

// ---------------- wave-per-node score: qA computed once per node into LDS;
// then 8 edges x 8 heads scored lane-parallel; lsum folded in ----------------
__global__ __launch_bounds__(256) void score2_kernel(
    const float* __restrict__ Qn, const float* __restrict__ KV,
    const float* __restrict__ ktv, const int4* __restrict__ meta,
    const int* __restrict__ node_type,
    const float* __restrict__ rel_pri, const float* __restrict__ rel_att,
    const int* __restrict__ row_start,
    float* __restrict__ p_out, float* __restrict__ inv_out) {
    __shared__ float qrow[4][128];
    __shared__ float qAs[4][512];    // [wave][r*128 + h*16 + i]
    int w = threadIdx.x >> 6;
    int lane = threadIdx.x & 63;
    int n = blockIdx.x * 4 + w;       // grid = NN/4 exactly

    // ---- block-uniform prologue (safe to barrier) ----
    *(float2*)&qrow[w][lane * 2] = *(const float2*)(Qn + (size_t)n * 128 + lane * 2);
    __syncthreads();
    #pragma unroll
    for (int u = 0; u < 8; ++u) {
        int f = u * 64 + lane;        // 0..511
        int rem = f & 127;
        int hh = rem >> 4;
        const float4* A4 = (const float4*)(rel_att + (size_t)f * 16);
        float4 a0 = A4[0], a1 = A4[1], a2 = A4[2], a3 = A4[3];
        const float* qq = &qrow[w][hh * 16];
        float val = a0.x * qq[0] + a0.y * qq[1] + a0.z * qq[2] + a0.w * qq[3]
                  + a1.x * qq[4] + a1.y * qq[5] + a1.z * qq[6] + a1.w * qq[7]
                  + a2.x * qq[8] + a2.y * qq[9] + a2.z * qq[10] + a2.w * qq[11]
                  + a3.x * qq[12] + a3.y * qq[13] + a3.z * qq[14] + a3.w * qq[15];
        qAs[w][f] = val;
    }
    __syncthreads();

    // ---- per-wave edge loop (no barriers) ----
    int tt = node_type[n];
    int e_beg = row_start[n], e_end = row_start[n + 1];
    int j = lane >> 3, h = lane & 7;
    float ls = 0.f;
    for (int cb = e_beg; cb < e_end; cb += 8) {
        int ei = cb + j;
        bool valid = ei < e_end;
        int4 m = valid ? meta[ei] : make_int4(0, 0, 0, 0);
        int r = m.y & 3, st = (m.y >> 2) & 3, tb = m.y >> 6;
        const float4* kp = (const float4*)(KV + (size_t)m.x * 256 + h * 16);
        const float4* tp = (const float4*)(ktv + (size_t)tb * 256 + h * 16);
        float4 k0 = kp[0], k1 = kp[1], k2 = kp[2], k3 = kp[3];
        float4 t0 = tp[0], t1 = tp[1], t2 = tp[2], t3 = tp[3];
        const float* qa = &qAs[w][r * 128 + h * 16];
        float s = (k0.x + t0.x) * qa[0]  + (k0.y + t0.y) * qa[1]
                + (k0.z + t0.z) * qa[2]  + (k0.w + t0.w) * qa[3]
                + (k1.x + t1.x) * qa[4]  + (k1.y + t1.y) * qa[5]
                + (k1.z + t1.z) * qa[6]  + (k1.w + t1.w) * qa[7]
                + (k2.x + t2.x) * qa[8]  + (k2.y + t2.y) * qa[9]
                + (k2.z + t2.z) * qa[10] + (k2.w + t2.w) * qa[11]
                + (k3.x + t3.x) * qa[12] + (k3.y + t3.y) * qa[13]
                + (k3.z + t3.z) * qa[14] + (k3.w + t3.w) * qa[15];
        float pri = rel_pri[((tt * 4 + r) * 3 + st) * 8 + h];
        float p = valid ? __expf(s * pri * 0.25f) : 0.f;
        if (valid) p_out[(size_t)ei * 8 + h] = p;   // == cb*8 + lane: coalesced
        ls += p;
    }
    // reduce over the 8 edge-slots (stride 8 lanes)
    ls += __shfl_xor(ls, 8, 64);
    ls += __shfl_xor(ls, 16, 64);
    ls += __shfl_xor(ls, 32, 64);
    if (j == 0) inv_out[n * 8 + h] = (ls > 0.f) ? (1.f / ls) : 0.f;
}

// ---------------- aggregation: wave per node; per-relation register accums;
// epilogue applies rel_msg via LDS (parallel across lanes, no shuffles) ----------------
__global__ __launch_bounds__(256) void aggr_kernel(
    const float* __restrict__ KV, const float* __restrict__ ktv,
    const int4* __restrict__ meta, const float* __restrict__ p,
    const float* __restrict__ inv, const int* __restrict__ row_start,
    const float* __restrict__ rel_msg, float* __restrict__ h_out) {
    __shared__ float accb[4][4][136];   // [wave][r][h*17 + cp] padded vs bank conflicts
    int w = threadIdx.x >> 6;
    int n = blockIdx.x * 4 + w;          // grid = NN/4 exactly; no early return (barrier!)
    int lane = threadIdx.x & 63;
    int d0 = lane * 2;
    int h = lane >> 3;
    int cp = d0 & 15;
    int e_beg = row_start[n], e_end = row_start[n + 1];
    float2 a0 = {0.f, 0.f}, a1 = {0.f, 0.f}, a2 = {0.f, 0.f}, a3 = {0.f, 0.f};
    int rmask = 0;
    for (int cb = e_beg; cb < e_end; cb += 64) {
        int cdeg = min(64, e_end - cb);
        int4 mm = (cb + lane < e_end) ? meta[cb + lane] : make_int4(0, 0, 0, 0);
        int mx = mm.x, my = mm.y;
        #pragma unroll 4
        for (int i = 0; i < cdeg; ++i) {
            int src  = __shfl(mx, i, 64);
            int code = __shfl(my, i, 64);
            int r = code & 3;
            float pv = p[(size_t)(cb + i) * 8 + h];
            float2 v1 = *(const float2*)(KV + (size_t)src * 256 + 128 + d0);
            float2 v2 = *(const float2*)(ktv + (size_t)(code >> 6) * 256 + 128 + d0);
            float vx = pv * (v1.x + v2.x);
            float vy = pv * (v1.y + v2.y);
            rmask |= (1 << r);
            switch (r) {
                case 0: a0.x += vx; a0.y += vy; break;
                case 1: a1.x += vx; a1.y += vy; break;
                case 2: a2.x += vx; a2.y += vy; break;
                default: a3.x += vx; a3.y += vy; break;
            }
        }
    }
    int li = h * 17 + cp;
    accb[w][0][li] = a0.x; accb[w][0][li + 1] = a0.y;
    accb[w][1][li] = a1.x; accb[w][1][li + 1] = a1.y;
    accb[w][2][li] = a2.x; accb[w][2][li + 1] = a2.y;
    accb[w][3][li] = a3.x; accb[w][3][li + 1] = a3.y;
    __syncthreads();
    // o[c] = sum_r sum_i acc_r[h*16+i] * rel_msg[r,h,i,c]
    float o0 = 0.f, o1 = 0.f;
    const float* M = rel_msg + h * 256 + cp;
    #pragma unroll
    for (int r = 0; r < 4; ++r) {
        if (rmask & (1 << r)) {
            #pragma unroll
            for (int i = 0; i < 16; ++i) {
                float av = accb[w][r][h * 17 + i];
                float2 mm2 = *(const float2*)(M + r * 2048 + i * 16);
                o0 += av * mm2.x;
                o1 += av * mm2.y;
            }
        }
    }
    float iv = inv[n * 8 + h];
    o0 *= iv; o1 *= iv;
    // exact gelu
    o0 = 0.5f * o0 * (1.f + erff(o0 * 0.7071067811865475f));
    o1 = 0.5f * o1 * (1.f + erff(o1 * 0.7071067811865475f));
    *(float2*)(h_out + (size_t)n * 128 + d0) = make_float2(o0, o1);
}

// ---------------- launcher ----------------
extern "C" void kernel_launch(void* const* d_in, const int* in_sizes, int n_in,
                              void* d_out, int out_size, void* d_ws, size_t ws_size,
                              hipStream_t stream) {
    const float* node_feature = (const float*)d_in[0];
    const int*   node_type    = (const int*)d_in[1];
    const int*   edge_index   = (const int*)d_in[2];   // [2,E]: src then tgt
    const int*   edge_type    = (const int*)d_in[3];
    const int*   edge_time    = (const int*)d_in[4];
    const float* adapt_w      = (const float*)d_in[5];
    const float* adapt_b      = (const float*)d_in[6];
    const float* Wk           = (const float*)d_in[7];
    const float* bk           = (const float*)d_in[8];
    const float* Wq           = (const float*)d_in[9];
    const float* bq           = (const float*)d_in[10];
    const float* Wv           = (const float*)d_in[11];
    const float* bv           = (const float*)d_in[12];
    const float* Wa           = (const float*)d_in[13];
    const float* ba           = (const float*)d_in[14];
    const float* rel_pri      = (const float*)d_in[15];
    const float* rel_att      = (const float*)d_in[16];
    const float* rel_msg      = (const float*)d_in[17];
    const float* skip         = (const float*)d_in[18];
    const float* rte_w        = (const float*)d_in[19];
    const float* rte_b        = (const float*)d_in[20];
    float* out = (float*)d_out;

    const size_t ND = (size_t)NN * 128;
    float* Qn     = (float*)d_ws;            // N*128 (reused as h buffer)
    float* KV     = Qn + ND;                 // N*256 (k|v per row)
    float* rtab   = KV + 2 * ND;             // 240*256
    float* rproj  = rtab + 240 * 256;        // 240*128
    float* ktv    = rproj + 240 * 128;       // 720*256 (k|v per row)
    float* pbuf   = ktv + 720 * 256;         // EE*8
    float* invl   = pbuf + (size_t)EE * 8;   // NN*8
    int*   cnt    = (int*)(invl + (size_t)NN * 8);
    int*   fill   = cnt + NN;
    int*   row_st = fill + NN;               // NN+1 (+pad)
    int*   order  = row_st + NN + 4;         // NN
    int*   tcnt   = order + NN;              // 3 (+pad)
    int*   fill3  = tcnt + 4;                // 3 (+pad)
    int4*  meta   = (int4*)(fill3 + 4);      // EE int4
    // total ~184 MB (R6 layout, proven; R5's 342 MB crashed)

    const int* esrc = edge_index;
    const int* etgt = edge_index + EE;

    hipMemsetAsync(cnt, 0, 2 * NN * sizeof(int), stream);
    hipMemsetAsync(tcnt, 0, 8 * sizeof(int), stream);
    rte_tab_kernel<<<240, 256, 0, stream>>>(rtab);
    hist_kernel<<<(EE + 255) / 256, 256, 0, stream>>>(etgt, cnt);
    scan_kernel<<<1, 1024, 0, stream>>>(cnt, row_st);
    scatter_meta_kernel<<<(EE + 255) / 256, 256, 0, stream>>>(esrc, etgt, edge_type,
                                                              edge_time, node_type,
                                                              row_st, fill, meta);
    node_hist_kernel<<<(NN + 255) / 256, 256, 0, stream>>>(node_type, tcnt);
    node_scatter_kernel<<<(NN + 255) / 256, 256, 0, stream>>>(node_type, tcnt, fill3, order);

    // input adaptation: x = tanh(typed_linear(node_feature))
    typed_lin_kernel<0><<<NN / 32, 256, 0, stream>>>(node_feature, node_type, order,
                                                     adapt_w, adapt_b, nullptr, out);

    for (int l = 0; l < 2; ++l) {
        const float* Wk_l = Wk + l * 49152;  const float* bk_l = bk + l * 384;
        const float* Wq_l = Wq + l * 49152;  const float* bq_l = bq + l * 384;
        const float* Wv_l = Wv + l * 49152;  const float* bv_l = bv + l * 384;
        const float* Wa_l = Wa + l * 49152;  const float* ba_l = ba + l * 384;
        const float* pri_l = rel_pri + l * 288;
        const float* att_l = rel_att + l * 8192;
        const float* msg_l = rel_msg + l * 8192;
        const float* skip_l = skip + l * 3;
        const float* rte_w_l = rte_w + l * 32768;
        const float* rte_b_l = rte_b + l * 128;

        rte_proj_kernel<<<240, 128, 0, stream>>>(rtab, rte_w_l, rte_b_l, rproj);
        ktv_kernel<<<720, 128, 0, stream>>>(rproj, Wk_l, Wv_l, ktv);
        qkv_kernel<<<NN / 32, 256, 0, stream>>>(out, node_type, order, Wq_l, bq_l,
                                                Wk_l, bk_l, Wv_l, bv_l, Qn, KV);
        score2_kernel<<<NN / 4, 256, 0, stream>>>(Qn, KV, ktv, meta, node_type,
                                                  pri_l, att_l, row_st, pbuf, invl);
        aggr_kernel<<<NN / 4, 256, 0, stream>>>(KV, ktv, meta, pbuf, invl, row_st,
                                                msg_l, Qn /* h overwrites Qn: safe */);
        typed_lin_kernel<1><<<NN / 32, 256, 0, stream>>>(Qn, node_type, order, Wa_l, ba_l,
                                                         skip_l, out);
    }
}